// Round 5
// baseline (79.430 us; speedup 1.0000x reference)
//
#include <hip/hip_runtime.h>
#include <cstdint>
#include <cstddef>
#include <algorithm>

// ---------------- problem constants ----------------
#define NROW 16      // only bn rows 0..15 feed the outputs (n=16)
#define CTOT 384
#define HW   1024    // 32*32
#define KSEL 20
#define PSEL 96
#define NREM 76      // P - K
#define NUNSEL 1004  // HW - K

#define CPB    8                 // channels per block
#define SPLIT  (CTOT / CPB)      // 48
#define RSTR   40                // padded LDS row stride (floats)
#define PROW   34                // padded rows: zero, 32 data, zero
#define PLANEF (PROW * RSTR)     // 1360 floats per plane

struct Perm76 { int p[NREM]; };

// ---------------- fused kernel: conv -> partial -> ticket -> (finisher) reduce+select ----------------
// grid = NROW*SPLIT (768) = exactly 3 blocks/CU (43.7 KB LDS). Block (r,s) convolves channels
// [s*CPB,(s+1)*CPB) of image r. The 48th block to arrive per image reduces + selects + emits.
__global__ __launch_bounds__(256) void pv_fused(
    const float* __restrict__ feat, const float* __restrict__ dw_w,
    const float* __restrict__ pw_w, float* __restrict__ partial,
    int* __restrict__ cnt, int* __restrict__ out, Perm76 perm)
{
  __shared__ __align__(16) char smem[CPB * PLANEF * 4];   // 43,520 B, phase-aliased
  __shared__ int votes[KSEL];
  __shared__ int wsumS[4];
  __shared__ int ncand, bstarS, CtotS, isFin;

  float* planes = reinterpret_cast<float*>(smem);
  const int t  = threadIdx.x;
  const int r  = blockIdx.x & (NROW - 1);
  const int s  = blockIdx.x >> 4;
  const int c0 = s * CPB;
  const float* base = feat + ((size_t)r * CTOT + c0) * HW;

  // ---- stage CPB planes: issue all global loads first (24 KB/block) ----
  float4 v[CPB];
  #pragma unroll
  for (int c = 0; c < CPB; ++c)
    v[c] = reinterpret_cast<const float4*>(base + (size_t)c * HW)[t];

  const int ch   = t >> 5;        // channel this thread computes (0..7)
  const int pos  = t & 31;
  const int band = pos >> 3;      // row band (0..3) -> rows band*8..band*8+7
  const int cg   = pos & 7;       // col group -> cols cg*4..cg*4+3

  // fused per-channel weights
  float w[9];
  {
    const float pw = pw_w[c0 + ch];
    #pragma unroll
    for (int i = 0; i < 9; ++i) w[i] = dw_w[(c0 + ch) * 9 + i] * pw;
  }

  // zero pad cells: rows 0,33 full (80) + halo cols 3,36 rows 1..32 (64) = 144/plane
  for (int z = t; z < CPB * 144; z += 256) {
    const int c = z / 144, k = z % 144;
    int row, col;
    if (k < 80) { row = (k < 40) ? 0 : 33; col = k - (k < 40 ? 0 : 40); }
    else        { const int k2 = k - 80; col = (k2 < 32) ? 3 : 36; row = 1 + (k2 & 31); }
    planes[c * PLANEF + row * RSTR + col] = 0.f;
  }

  // park loaded planes (16B-aligned: data cols start at padded col 4)
  {
    const int row = (t >> 3) + 1, col4 = ((t & 7) << 2) + 4;
    #pragma unroll
    for (int c = 0; c < CPB; ++c)
      *reinterpret_cast<float4*>(&planes[c * PLANEF + row * RSTR + col4]) = v[c];
  }
  __syncthreads();

  // ---- conv: 4 cols x 8 rows per thread; 1 b128 + 2 b32 LDS reads per padded row ----
  const float* pl = planes + ch * PLANEF + (band * 8) * RSTR + 4 + cg * 4;
  float rowv[10][6];
  #pragma unroll
  for (int m = 0; m < 10; ++m) {
    const float* rw = pl + m * RSTR;
    rowv[m][0] = rw[-1];
    const float4 f = *reinterpret_cast<const float4*>(rw);
    rowv[m][1] = f.x; rowv[m][2] = f.y; rowv[m][3] = f.z; rowv[m][4] = f.w;
    rowv[m][5] = rw[4];
  }
  float acc[8][4];
  #pragma unroll
  for (int j = 0; j < 8; ++j) {
    #pragma unroll
    for (int k = 0; k < 4; ++k) {
      float a = 0.f;
      #pragma unroll
      for (int d = 0; d < 3; ++d)
        a += rowv[j + d][k]     * w[3 * d]
           + rowv[j + d][k + 1] * w[3 * d + 1]
           + rowv[j + d][k + 2] * w[3 * d + 2];
      acc[j][k] = a;
    }
  }
  __syncthreads();                       // all conv reads of planes done

  // ---- cross-channel sum via XOR-swizzled outbuf (aliases planes) ----
  float* outb = planes;                  // [8][1024] floats, swizzled
  {
    const int colp = (cg * 4) ^ (ch << 2);
    #pragma unroll
    for (int j = 0; j < 8; ++j) {
      const int row = band * 8 + j;
      *reinterpret_cast<float4*>(&outb[ch * HW + row * 32 + colp]) =
          make_float4(acc[j][0], acc[j][1], acc[j][2], acc[j][3]);
    }
  }
  __syncthreads();
  float* pblk = partial + ((size_t)(r * SPLIT + s)) * HW;
  #pragma unroll
  for (int q = 0; q < 4; ++q) {
    const int px = t + 256 * q;
    float sum = 0.f;
    #pragma unroll
    for (int c = 0; c < CPB; ++c)
      sum += outb[c * HW + (px ^ (c << 2))];   // conflict-free b32 across lanes
    pblk[px] = sum;
  }

  // ---- ticket: release stores, arrive; 48th arriver per image finishes ----
  __threadfence();                       // device-scope release of this thread's stores
  __syncthreads();
  if (t == 0) {
    const int old = atomicAdd(&cnt[r], 1);
    isFin = (old == SPLIT - 1);
  }
  __syncthreads();
  if (!isFin) return;
  __threadfence();                       // acquire: invalidate L1, see all partials

  // ---- finisher: reduce 48 partial planes (192 KB, L2-resident) ----
  const float* prow = partial + ((size_t)r * SPLIT) * HW;
  float4 A0 = make_float4(0, 0, 0, 0), A1 = A0, A2 = A0, A3 = A0;
  #pragma unroll
  for (int s2 = 0; s2 < SPLIT; s2 += 4) {
    const float4 u0 = reinterpret_cast<const float4*>(prow + (size_t)(s2 + 0) * HW)[t];
    const float4 u1 = reinterpret_cast<const float4*>(prow + (size_t)(s2 + 1) * HW)[t];
    const float4 u2 = reinterpret_cast<const float4*>(prow + (size_t)(s2 + 2) * HW)[t];
    const float4 u3 = reinterpret_cast<const float4*>(prow + (size_t)(s2 + 3) * HW)[t];
    A0.x += u0.x; A0.y += u0.y; A0.z += u0.z; A0.w += u0.w;
    A1.x += u1.x; A1.y += u1.y; A1.z += u1.z; A1.w += u1.w;
    A2.x += u2.x; A2.y += u2.y; A2.z += u2.z; A2.w += u2.w;
    A3.x += u3.x; A3.y += u3.y; A3.z += u3.z; A3.w += u3.w;
  }
  const float sv[4] = { ((A0.x + A1.x) + (A2.x + A3.x)),
                        ((A0.y + A1.y) + (A2.y + A3.y)),
                        ((A0.z + A1.z) + (A2.z + A3.z)),
                        ((A0.w + A1.w) + (A2.w + A3.w)) };

  // ---- select phase (smem re-carved; proven logic from R4) ----
  uint32_t*           hist  = reinterpret_cast<uint32_t*>(smem);                 // 16 KB
  unsigned long long* keysh = reinterpret_cast<unsigned long long*>(smem + 16384); // 8 KB
  unsigned long long* cand  = reinterpret_cast<unsigned long long*>(smem + 24576); // 2 KB
  int*                maskv = reinterpret_cast<int*>(smem + 26624);              // 4 KB
  int*                unsel = reinterpret_cast<int*>(smem + 30720);              // 4016 B

  const int lane = t & 63, wv = t >> 6;

  uint32_t m[4];
  unsigned long long key[4];
  #pragma unroll
  for (int q = 0; q < 4; ++q) {
    const int i = 4 * t + q;
    const uint32_t b = __float_as_uint(sv[q]);
    m[q] = (b & 0x80000000u) ? ~b : (b | 0x80000000u);
    key[q] = ((unsigned long long)m[q] << 32) | (uint32_t)(1023 - i);
    keysh[i] = key[q];
  }
  for (int j = t; j < 4096; j += 256) hist[j] = 0;
  maskv[t] = 0; maskv[t + 256] = 0; maskv[t + 512] = 0; maskv[t + 768] = 0;
  if (t == 0) ncand = 0;
  __syncthreads();

  #pragma unroll
  for (int q = 0; q < 4; ++q) atomicAdd(&hist[m[q] >> 20], 1u);
  __syncthreads();

  // suffix-scan to find threshold bin b*
  uint32_t loc[16]; uint32_t tsum = 0;
  #pragma unroll
  for (int j = 0; j < 16; ++j) { loc[j] = hist[t * 16 + j]; tsum += loc[j]; }
  uint32_t ssum = tsum;
  #pragma unroll
  for (int d = 1; d < 64; d <<= 1) {
    const uint32_t o = __shfl_down(ssum, d);
    if (lane + d < 64) ssum += o;
  }
  if (lane == 0) wsumS[wv] = (int)ssum;
  __syncthreads();
  uint32_t above = 0;
  for (int w2 = wv + 1; w2 < 4; ++w2) above += (uint32_t)wsumS[w2];
  uint32_t run = ssum + above - tsum;
  #pragma unroll
  for (int j = 15; j >= 0; --j) {
    run += loc[j];
    if (run >= KSEL && run - loc[j] < KSEL) { bstarS = t * 16 + j; CtotS = (int)run; }
  }
  __syncthreads();
  const int bstar = bstarS, C = CtotS;

  if (C <= 256) {
    #pragma unroll
    for (int q = 0; q < 4; ++q)
      if ((int)(m[q] >> 20) >= bstar) { const int p = atomicAdd(&ncand, 1); cand[p] = key[q]; }
    __syncthreads();
    if (t < C) {
      const unsigned long long my = cand[t];
      int rank = 0;
      for (int j = 0; j < C; ++j) rank += (cand[j] > my);
      if (rank < KSEL) votes[rank] = 1023 - (int)(my & 1023ull);
    }
  } else {
    if (t < 64) {
      unsigned long long keys[16];
      #pragma unroll
      for (int j = 0; j < 16; ++j) keys[j] = keysh[t * 16 + j];
      for (int k = 0; k < KSEL; ++k) {
        unsigned long long best = 0ull;
        #pragma unroll
        for (int j = 0; j < 16; ++j) best = keys[j] > best ? keys[j] : best;
        #pragma unroll
        for (int off = 32; off; off >>= 1) {
          const unsigned long long o = __shfl_xor(best, off);
          if (o > best) best = o;
        }
        #pragma unroll
        for (int j = 0; j < 16; ++j) if (keys[j] == best) keys[j] = 0ull;
        if (t == 0) votes[k] = 1023 - (int)(best & 1023ull);
      }
    }
  }
  __syncthreads();

  // selected coords + mask
  if (t < KSEL) {
    const int idx = votes[t];
    maskv[idx] = 1;
    int xx = idx & 31, yy = idx >> 5;
    if (xx < 1) xx = 1;
    if (yy < 1) yy = 1;
    out[r * PSEL + t]               = xx;
    out[NROW * PSEL + r * PSEL + t] = yy;
  }
  __syncthreads();

  // unselected indices ascending via shfl prefix over !mask
  int cntu = 0;
  #pragma unroll
  for (int j = 0; j < 4; ++j) cntu += (maskv[t * 4 + j] == 0);
  int inc = cntu;
  #pragma unroll
  for (int d = 1; d < 64; d <<= 1) {
    const int o = __shfl_up(inc, d);
    if (lane >= d) inc += o;
  }
  if (lane == 63) wsumS[wv] = inc;
  __syncthreads();
  int basep = 0;
  for (int i = 0; i < 4; ++i) if (i < wv) basep += wsumS[i];
  int posu = basep + inc - cntu;
  #pragma unroll
  for (int j = 0; j < 4; ++j) {
    const int i = t * 4 + j;
    if (!maskv[i]) unsel[posu++] = i;
  }
  __syncthreads();

  // random remaining via fixed permutation
  if (t < NREM) {
    const int u = unsel[perm.p[t]];
    int xx = u & 31, yy = u >> 5;
    if (xx < 1) xx = 1;
    if (yy < 1) yy = 1;
    out[r * PSEL + KSEL + t]               = xx;
    out[NROW * PSEL + r * PSEL + KSEL + t] = yy;
  }
}

// ---------------- host: JAX threefry2x32 (partitionable) ----------------
static inline uint32_t rotl32(uint32_t v, uint32_t n) { return (v << n) | (v >> (32 - n)); }

static void tf2x32(uint32_t k0, uint32_t k1, uint32_t x0, uint32_t x1,
                   uint32_t* o0, uint32_t* o1)
{
  const uint32_t ks[3] = { k0, k1, k0 ^ k1 ^ 0x1BD11BDAu };
  static const uint32_t rot[2][4] = { {13, 15, 26, 6}, {17, 29, 16, 24} };
  x0 += ks[0]; x1 += ks[1];
  for (int i = 0; i < 5; ++i) {
    const uint32_t* rr = rot[i & 1];
    for (int j = 0; j < 4; ++j) { x0 += x1; x1 = rotl32(x1, rr[j]); x1 ^= x0; }
    x0 += ks[(i + 1) % 3];
    x1 += ks[(i + 2) % 3] + (uint32_t)(i + 1);
  }
  *o0 = x0; *o1 = x1;
}

// perm = jax.random.permutation(jax.random.key(42), 1004)[:76]  (threefry_partitionable)
static void compute_perm(int* perm_out)
{
  uint32_t bits[NUNSEL];
  uint32_t sk0, sk1;
  { uint32_t o0, o1; tf2x32(0u, 42u, 0u, 1u, &o0, &o1); sk0 = o0; sk1 = o1; }
  for (int i = 0; i < NUNSEL; ++i) {
    uint32_t o0, o1; tf2x32(sk0, sk1, 0u, (uint32_t)i, &o0, &o1);
    bits[i] = o0 ^ o1;
  }
  int idx[NUNSEL];
  for (int i = 0; i < NUNSEL; ++i) idx[i] = i;
  std::stable_sort(idx, idx + NUNSEL, [&](int a, int b) { return bits[a] < bits[b]; });
  for (int j = 0; j < NREM; ++j) perm_out[j] = idx[j];
}

extern "C" void kernel_launch(void* const* d_in, const int* in_sizes, int n_in,
                              void* d_out, int out_size, void* d_ws, size_t ws_size,
                              hipStream_t stream)
{
  (void)in_sizes; (void)n_in; (void)out_size; (void)ws_size;
  const float* feat = (const float*)d_in[0];
  const float* dw_w = (const float*)d_in[1];
  // d_in[2] = dw_b (zeros; constant shift, ordering-irrelevant)
  const float* pw_w = (const float*)d_in[3];
  // d_in[4] = pw_b (constant shift, ordering-irrelevant)
  int*   out     = (int*)d_out;
  float* partial = (float*)d_ws;                               // 16*48*4 KB = 3 MB
  int*   cnt     = (int*)((char*)d_ws + (size_t)NROW * SPLIT * HW * sizeof(float));

  Perm76 perm;
  compute_perm(perm.p);                    // deterministic host compute, kernel-arg baked

  hipMemsetAsync(cnt, 0, NROW * sizeof(int), stream);
  pv_fused<<<NROW * SPLIT, 256, 0, stream>>>(feat, dw_w, pw_w, partial, cnt, out, perm);
}

// Round 6
// 22.583 us; speedup vs baseline: 3.5172x; 3.5172x over previous
//
#include <hip/hip_runtime.h>
#include <cstdint>
#include <cstddef>
#include <algorithm>

// ---------------- problem constants ----------------
#define NROW 16      // only bn rows 0..15 feed the outputs (n=16)
#define CTOT 384
#define HW   1024    // 32*32
#define KSEL 20
#define PSEL 96
#define NREM 76      // P - K
#define NUNSEL 1004  // HW - K

#define CPB    4                 // channels per block (kernel A)
#define SPLIT  (CTOT / CPB)      // 96
#define RSTR   40                // padded LDS row stride (floats)
#define PROW   34                // padded rows: zero, 32 data, zero
#define PLANEF (PROW * RSTR)     // 1360 floats per plane

typedef unsigned long long u64;

struct Perm76 { int p[NREM]; };

// ---------------- kernel A: fused dw3x3+pw conv -> private partial planes ----------------
// grid = NROW*SPLIT (1536) = 6 blocks/CU (24 waves/CU), 21.8 KB LDS. Block (r,s) convolves
// channels [s*4,(s+1)*4) of image r; writes one 4 KB f32 partial plane (float4 stores).
__global__ __launch_bounds__(256) void pv_convA(
    const float* __restrict__ feat, const float* __restrict__ dw_w,
    const float* __restrict__ pw_w, float* __restrict__ partial)
{
  __shared__ __align__(16) float planes[CPB * PLANEF];   // 21,760 B (aliased as outbuf later)
  const int t  = threadIdx.x;
  const int r  = blockIdx.x & (NROW - 1);
  const int s  = blockIdx.x >> 4;
  const int c0 = s * CPB;
  const float* base = feat + ((size_t)r * CTOT + c0) * HW;

  // issue all plane loads first (16 KB/block, 25 MB total)
  float4 v[CPB];
  #pragma unroll
  for (int c = 0; c < CPB; ++c)
    v[c] = reinterpret_cast<const float4*>(base + (size_t)c * HW)[t];

  const int ch  = t >> 6;         // channel this thread computes (0..3)
  const int pos = t & 63;
  const int band = pos >> 3;      // 8 row bands of 4 rows
  const int cg   = pos & 7;       // 8 col groups of 4 cols

  // fused per-channel weights
  float w[9];
  {
    const float pw = pw_w[c0 + ch];
    #pragma unroll
    for (int i = 0; i < 9; ++i) w[i] = dw_w[(c0 + ch) * 9 + i] * pw;
  }

  // zero pad cells: rows 0,33 full (80) + halo cols 3,36 rows 1..32 (64) = 144/plane
  for (int z = t; z < CPB * 144; z += 256) {
    const int c = z / 144, k = z % 144;
    int row, col;
    if (k < 80) { row = (k < 40) ? 0 : 33; col = k - (k < 40 ? 0 : 40); }
    else        { const int k2 = k - 80; col = (k2 < 32) ? 3 : 36; row = 1 + (k2 & 31); }
    planes[c * PLANEF + row * RSTR + col] = 0.f;
  }

  // park loaded planes (16B-aligned: data cols start at padded col 4)
  {
    const int prow = (t >> 3) + 1, col4 = ((t & 7) << 2) + 4;
    #pragma unroll
    for (int c = 0; c < CPB; ++c)
      *reinterpret_cast<float4*>(&planes[c * PLANEF + prow * RSTR + col4]) = v[c];
  }
  __syncthreads();

  // conv: 4x4 tile per thread, rolling-row (low VGPR); 1 b128 + 2 b32 per padded row
  const float* pl = planes + ch * PLANEF + (band * 4) * RSTR + 4 + cg * 4;
  float acc[4][4];
  #pragma unroll
  for (int j = 0; j < 4; ++j)
    #pragma unroll
    for (int k = 0; k < 4; ++k) acc[j][k] = 0.f;

  #pragma unroll
  for (int m = 0; m < 6; ++m) {              // padded rows band*4 .. band*4+5
    float c6[6];
    const float* rw = pl + m * RSTR;
    c6[0] = rw[-1];
    const float4 f = *reinterpret_cast<const float4*>(rw);
    c6[1] = f.x; c6[2] = f.y; c6[3] = f.z; c6[4] = f.w;
    c6[5] = rw[4];
    #pragma unroll
    for (int j = 0; j < 4; ++j) {
      const int d = m - j;                   // kernel row
      if (d >= 0 && d < 3) {
        #pragma unroll
        for (int k = 0; k < 4; ++k)
          acc[j][k] += c6[k] * w[3 * d] + c6[k + 1] * w[3 * d + 1] + c6[k + 2] * w[3 * d + 2];
      }
    }
  }
  __syncthreads();                           // all conv reads of planes done

  // cross-channel sum via row-XOR-swizzled outbuf (aliases planes); float4 throughout
  float* outb = planes;                      // [4][1024] floats, row swizzled by ^ch
  #pragma unroll
  for (int j = 0; j < 4; ++j) {
    const int row = band * 4 + j;
    *reinterpret_cast<float4*>(&outb[ch * HW + ((row ^ ch) * 32) + cg * 4]) =
        make_float4(acc[j][0], acc[j][1], acc[j][2], acc[j][3]);
  }
  __syncthreads();
  {
    const int row = t >> 3, col4 = (t & 7) << 2;
    float4 sum = make_float4(0.f, 0.f, 0.f, 0.f);
    #pragma unroll
    for (int c = 0; c < CPB; ++c) {
      const float4 u = *reinterpret_cast<const float4*>(&outb[c * HW + ((row ^ c) * 32) + col4]);
      sum.x += u.x; sum.y += u.y; sum.z += u.z; sum.w += u.w;
    }
    reinterpret_cast<float4*>(partial + ((size_t)(r * SPLIT + s)) * HW)[t] = sum;
  }
}

// ---------------- kernel B1: reduce 96 planes per 128-px slice + slice-local exact top-20 ----------------
// grid = 128 blocks (8 slices per image), 256 threads. Writes 20 u64 keys per slice, rank-ordered.
__global__ __launch_bounds__(256) void pv_reduceTopk(
    const float* __restrict__ partial, u64* __restrict__ cand)
{
  __shared__ float sums[2][128];
  __shared__ u64 keysh[128];
  const int r = blockIdx.x >> 3;
  const int q = blockIdx.x & 7;
  const int t = threadIdx.x;
  const int half = t >> 7, tt = t & 127;

  // planes half*48 .. half*48+47, pixel q*128+tt; coalesced b32 reads
  const float* basep = partial + ((size_t)(r * SPLIT + half * 48)) * HW + q * 128 + tt;
  float a = 0.f, b = 0.f, c = 0.f, d = 0.f;
  #pragma unroll
  for (int s = 0; s < 48; s += 4) {
    a += basep[(size_t)(s + 0) * HW];
    b += basep[(size_t)(s + 1) * HW];
    c += basep[(size_t)(s + 2) * HW];
    d += basep[(size_t)(s + 3) * HW];
  }
  sums[half][tt] = (a + b) + (c + d);
  __syncthreads();

  if (t < 128) {
    const float sv = sums[0][t] + sums[1][t];
    const uint32_t bb = __float_as_uint(sv);
    const uint32_t mm = (bb & 0x80000000u) ? ~bb : (bb | 0x80000000u);
    const int gpx = q * 128 + t;             // global pixel index
    keysh[t] = ((u64)mm << 32) | (uint32_t)(1023 - gpx);  // larger wins; tie -> smaller idx
  }
  __syncthreads();
  if (t < 128) {
    const u64 my = keysh[t];
    int rank = 0;
    for (int j = 0; j < 128; ++j) rank += (keysh[j] > my);   // broadcast reads, keys unique
    if (rank < KSEL) cand[((size_t)(r * 8 + q)) * KSEL + rank] = my;
  }
}

// ---------------- kernel B2: global top-20 from 160 candidates, selection, emit coords ----------------
// grid = NROW blocks, 256 threads. Output: x_out (16*96) then y_out (16*96), int32.
__global__ __launch_bounds__(256) void pv_selectB2(
    const u64* __restrict__ cand, int* __restrict__ out, Perm76 perm)
{
  __shared__ u64 keysh[8 * KSEL];            // 160 candidates
  __shared__ int votes[KSEL];
  __shared__ int maskv[HW];
  __shared__ int wsumS[4];
  __shared__ int unsel[NUNSEL];

  const int r = blockIdx.x;
  const int t = threadIdx.x;
  const int lane = t & 63, wv = t >> 6;

  if (t < 8 * KSEL) keysh[t] = cand[(size_t)r * 8 * KSEL + t];
  maskv[t] = 0; maskv[t + 256] = 0; maskv[t + 512] = 0; maskv[t + 768] = 0;
  __syncthreads();

  // exact global top-20: union of slice top-20s contains the global top-20
  if (t < 8 * KSEL) {
    const u64 my = keysh[t];
    int rank = 0;
    for (int j = 0; j < 8 * KSEL; ++j) rank += (keysh[j] > my);  // broadcast, keys unique
    if (rank < KSEL) votes[rank] = 1023 - (int)(my & 1023ull);
  }
  __syncthreads();

  // selected coords + mask
  if (t < KSEL) {
    const int idx = votes[t];
    maskv[idx] = 1;
    int xx = idx & 31, yy = idx >> 5;
    if (xx < 1) xx = 1;                      // clip(.,1,31); upper bound can't trigger
    if (yy < 1) yy = 1;
    out[r * PSEL + t]               = xx;
    out[NROW * PSEL + r * PSEL + t] = yy;
  }
  __syncthreads();

  // unselected indices ascending via shfl prefix over !mask
  int cnt = 0;
  #pragma unroll
  for (int j = 0; j < 4; ++j) cnt += (maskv[t * 4 + j] == 0);
  int inc = cnt;
  #pragma unroll
  for (int dd = 1; dd < 64; dd <<= 1) {
    const int o = __shfl_up(inc, dd);
    if (lane >= dd) inc += o;
  }
  if (lane == 63) wsumS[wv] = inc;
  __syncthreads();
  int basep = 0;
  for (int i = 0; i < 4; ++i) if (i < wv) basep += wsumS[i];
  int pos = basep + inc - cnt;               // exclusive prefix
  #pragma unroll
  for (int j = 0; j < 4; ++j) {
    const int i = t * 4 + j;
    if (!maskv[i]) unsel[pos++] = i;
  }
  __syncthreads();

  // random remaining via fixed permutation
  if (t < NREM) {
    const int u = unsel[perm.p[t]];
    int xx = u & 31, yy = u >> 5;
    if (xx < 1) xx = 1;
    if (yy < 1) yy = 1;
    out[r * PSEL + KSEL + t]               = xx;
    out[NROW * PSEL + r * PSEL + KSEL + t] = yy;
  }
}

// ---------------- host: JAX threefry2x32 (partitionable) ----------------
static inline uint32_t rotl32(uint32_t v, uint32_t n) { return (v << n) | (v >> (32 - n)); }

static void tf2x32(uint32_t k0, uint32_t k1, uint32_t x0, uint32_t x1,
                   uint32_t* o0, uint32_t* o1)
{
  const uint32_t ks[3] = { k0, k1, k0 ^ k1 ^ 0x1BD11BDAu };
  static const uint32_t rot[2][4] = { {13, 15, 26, 6}, {17, 29, 16, 24} };
  x0 += ks[0]; x1 += ks[1];
  for (int i = 0; i < 5; ++i) {
    const uint32_t* rr = rot[i & 1];
    for (int j = 0; j < 4; ++j) { x0 += x1; x1 = rotl32(x1, rr[j]); x1 ^= x0; }
    x0 += ks[(i + 1) % 3];
    x1 += ks[(i + 2) % 3] + (uint32_t)(i + 1);
  }
  *o0 = x0; *o1 = x1;
}

// perm = jax.random.permutation(jax.random.key(42), 1004)[:76]  (threefry_partitionable)
static void compute_perm(int* perm_out)
{
  uint32_t bits[NUNSEL];
  uint32_t sk0, sk1;
  { uint32_t o0, o1; tf2x32(0u, 42u, 0u, 1u, &o0, &o1); sk0 = o0; sk1 = o1; }
  for (int i = 0; i < NUNSEL; ++i) {
    uint32_t o0, o1; tf2x32(sk0, sk1, 0u, (uint32_t)i, &o0, &o1);
    bits[i] = o0 ^ o1;
  }
  int idx[NUNSEL];
  for (int i = 0; i < NUNSEL; ++i) idx[i] = i;
  std::stable_sort(idx, idx + NUNSEL, [&](int a, int b) { return bits[a] < bits[b]; });
  for (int j = 0; j < NREM; ++j) perm_out[j] = idx[j];
}

extern "C" void kernel_launch(void* const* d_in, const int* in_sizes, int n_in,
                              void* d_out, int out_size, void* d_ws, size_t ws_size,
                              hipStream_t stream)
{
  (void)in_sizes; (void)n_in; (void)out_size; (void)ws_size;
  const float* feat = (const float*)d_in[0];
  const float* dw_w = (const float*)d_in[1];
  // d_in[2] = dw_b (zeros; constant shift, ordering-irrelevant)
  const float* pw_w = (const float*)d_in[3];
  // d_in[4] = pw_b (constant shift, ordering-irrelevant)
  int*   out     = (int*)d_out;
  float* partial = (float*)d_ws;                                // 16*96*4 KB = 6 MB, fully rewritten
  u64*   cand    = (u64*)((char*)d_ws + (size_t)NROW * SPLIT * HW * sizeof(float)); // 16*160 u64

  Perm76 perm;
  compute_perm(perm.p);                      // deterministic host compute, kernel-arg baked

  pv_convA<<<NROW * SPLIT, 256, 0, stream>>>(feat, dw_w, pw_w, partial);
  pv_reduceTopk<<<128, 256, 0, stream>>>(partial, cand);
  pv_selectB2<<<NROW, 256, 0, stream>>>(cand, out, perm);
}

// Round 7
// 18.016 us; speedup vs baseline: 4.4089x; 1.2535x over previous
//
#include <hip/hip_runtime.h>
#include <cstdint>
#include <cstddef>
#include <algorithm>

// ---------------- problem constants ----------------
#define NROW 16      // only bn rows 0..15 feed the outputs (n=16)
#define CTOT 384
#define HW   1024    // 32*32
#define KSEL 20
#define PSEL 96
#define NREM 76      // P - K
#define NUNSEL 1004  // HW - K

#define CPB   8                  // channels per block (kernel A)
#define SPLIT (CTOT / CPB)       // 48

typedef unsigned long long u64;

struct Perm76 { int p[NREM]; };

// ---------------- conv job: 4x4 tile of one channel, rows in registers, halos via shfl ----------------
__device__ __forceinline__ void conv_job(const float4* f6, const float* w9,
                                         int b, int c, float acc[4][4])
{
  #pragma unroll
  for (int m = 0; m < 6; ++m) {
    float4 f = f6[m];
    const bool dead = (b == 0 && m == 0) || (b == 7 && m == 5);   // out-of-plane row
    if (dead) { f.x = 0.f; f.y = 0.f; f.z = 0.f; f.w = 0.f; }
    float L = __shfl_up(f.w, 1);     // col 4c-1 from lane-1 (row-mask inherited)
    float R = __shfl_down(f.x, 1);   // col 4c+4 from lane+1
    if (c == 0) L = 0.f;
    if (c == 7) R = 0.f;
    const float c6[6] = { L, f.x, f.y, f.z, f.w, R };
    #pragma unroll
    for (int j = 0; j < 4; ++j) {
      const int d = m - j;           // kernel row
      if (d >= 0 && d < 3) {
        #pragma unroll
        for (int k = 0; k < 4; ++k)
          acc[j][k] += c6[k]     * w9[3 * d]
                     + c6[k + 1] * w9[3 * d + 1]
                     + c6[k + 2] * w9[3 * d + 2];
      }
    }
  }
}

// ---------------- kernel A: shuffle-conv, no LDS staging -> partial planes ----------------
// grid = NROW*SPLIT (768) blocks = 3/CU. Block (r,s): channels [s*8,(s+1)*8); wave w does
// channels s*8+2w, s*8+2w+1. Cross-wave sum via 16 KB LDS, float4 partial store.
__global__ __launch_bounds__(256) void pv_conv(
    const float* __restrict__ feat, const float* __restrict__ dw_w,
    const float* __restrict__ pw_w, float* __restrict__ partial)
{
  __shared__ float red[4][HW];                  // 16 KB
  const int t = threadIdx.x;
  const int w = t >> 6, lane = t & 63;
  const int b = lane >> 3, c = lane & 7;        // 4x4 tile at rows 4b.., cols 4c..
  const int r = blockIdx.x & (NROW - 1);
  const int s = blockIdx.x >> 4;
  const int chA = s * CPB + 2 * w;
  const float* baseA = feat + ((size_t)r * CTOT + chA) * HW;
  const float* baseB = baseA + HW;

  // issue all 12 row-loads first (coalesced float4; halo rows dedup in L1/L2)
  float4 fa[6], fb[6];
  #pragma unroll
  for (int m = 0; m < 6; ++m) {
    const int row = 4 * b + m - 1;
    const int rc = row < 0 ? 0 : (row > 31 ? 31 : row);
    fa[m] = *reinterpret_cast<const float4*>(baseA + rc * 32 + 4 * c);
  }
  #pragma unroll
  for (int m = 0; m < 6; ++m) {
    const int row = 4 * b + m - 1;
    const int rc = row < 0 ? 0 : (row > 31 ? 31 : row);
    fb[m] = *reinterpret_cast<const float4*>(baseB + rc * 32 + 4 * c);
  }

  // fused weights (wave-uniform addresses -> cached)
  float wA[9], wB[9];
  {
    const float pa = pw_w[chA], pb = pw_w[chA + 1];
    #pragma unroll
    for (int i = 0; i < 9; ++i) {
      wA[i] = dw_w[chA * 9 + i] * pa;
      wB[i] = dw_w[(chA + 1) * 9 + i] * pb;
    }
  }

  float acc[4][4];
  #pragma unroll
  for (int j = 0; j < 4; ++j)
    #pragma unroll
    for (int k = 0; k < 4; ++k) acc[j][k] = 0.f;

  conv_job(fa, wA, b, c, acc);
  conv_job(fb, wB, b, c, acc);

  // cross-wave reduction (disjoint buffers; uniform-bank float4 traffic)
  #pragma unroll
  for (int j = 0; j < 4; ++j)
    *reinterpret_cast<float4*>(&red[w][(4 * b + j) * 32 + 4 * c]) =
        make_float4(acc[j][0], acc[j][1], acc[j][2], acc[j][3]);
  __syncthreads();

  float4 sum = make_float4(0.f, 0.f, 0.f, 0.f);
  #pragma unroll
  for (int g = 0; g < 4; ++g) {
    const float4 v = *reinterpret_cast<const float4*>(&red[g][4 * t]);
    sum.x += v.x; sum.y += v.y; sum.z += v.z; sum.w += v.w;
  }
  *reinterpret_cast<float4*>(partial + ((size_t)(r * SPLIT + s)) * HW + 4 * t) = sum;
}

// ---------------- kernel B1: coalesced reduce of 48 planes per 128-px slice + slice top-20 ----------------
// grid = 128 blocks (8 slices per image), 256 threads. Writes 20 rank-ordered u64 keys per slice.
__global__ __launch_bounds__(256) void pv_reduceTopk(
    const float* __restrict__ partial, u64* __restrict__ cand)
{
  __shared__ float red[8][128];
  __shared__ u64 keysh[128];
  const int r = blockIdx.x >> 3;
  const int q = blockIdx.x & 7;
  const int t = threadIdx.x;
  const int sg = t >> 5, l32 = t & 31;

  // group sg reduces planes sg, sg+8, ..., sg+40 over its 128-px slice (float4 coalesced)
  const float* bp = partial + ((size_t)(r * SPLIT + sg)) * HW + q * 128 + 4 * l32;
  float4 a = make_float4(0.f, 0.f, 0.f, 0.f);
  #pragma unroll
  for (int i = 0; i < 6; ++i) {
    const float4 v = *reinterpret_cast<const float4*>(bp + (size_t)(8 * i) * HW);
    a.x += v.x; a.y += v.y; a.z += v.z; a.w += v.w;
  }
  *reinterpret_cast<float4*>(&red[sg][4 * l32]) = a;
  __syncthreads();

  if (t < 128) {
    float sc = 0.f;
    #pragma unroll
    for (int g = 0; g < 8; ++g) sc += red[g][t];
    const uint32_t bb = __float_as_uint(sc);
    const uint32_t mm = (bb & 0x80000000u) ? ~bb : (bb | 0x80000000u);
    const int gpx = q * 128 + t;
    keysh[t] = ((u64)mm << 32) | (uint32_t)(1023 - gpx);  // larger wins; tie -> smaller idx
  }
  __syncthreads();
  if (t < 128) {
    const u64 my = keysh[t];
    int rank = 0;
    for (int j = 0; j < 128; ++j) rank += (keysh[j] > my);  // broadcast reads, unique keys
    if (rank < KSEL) cand[((size_t)(r * 8 + q)) * KSEL + rank] = my;
  }
}

// ---------------- kernel B2: global top-20 from 160 candidates, selection, emit coords ----------------
// grid = NROW blocks, 256 threads. Output: x_out (16*96) then y_out (16*96), int32.
__global__ __launch_bounds__(256) void pv_selectB2(
    const u64* __restrict__ cand, int* __restrict__ out, Perm76 perm)
{
  __shared__ u64 keysh[8 * KSEL];            // 160 candidates
  __shared__ int votes[KSEL];
  __shared__ int maskv[HW];
  __shared__ int wsumS[4];
  __shared__ int unsel[NUNSEL];

  const int r = blockIdx.x;
  const int t = threadIdx.x;
  const int lane = t & 63, wv = t >> 6;

  if (t < 8 * KSEL) keysh[t] = cand[(size_t)r * 8 * KSEL + t];
  maskv[t] = 0; maskv[t + 256] = 0; maskv[t + 512] = 0; maskv[t + 768] = 0;
  __syncthreads();

  // exact global top-20: union of slice top-20s contains the global top-20
  if (t < 8 * KSEL) {
    const u64 my = keysh[t];
    int rank = 0;
    for (int j = 0; j < 8 * KSEL; ++j) rank += (keysh[j] > my);
    if (rank < KSEL) votes[rank] = 1023 - (int)(my & 1023ull);
  }
  __syncthreads();

  // selected coords + mask
  if (t < KSEL) {
    const int idx = votes[t];
    maskv[idx] = 1;
    int xx = idx & 31, yy = idx >> 5;
    if (xx < 1) xx = 1;                      // clip(.,1,31); upper bound can't trigger
    if (yy < 1) yy = 1;
    out[r * PSEL + t]               = xx;
    out[NROW * PSEL + r * PSEL + t] = yy;
  }
  __syncthreads();

  // unselected indices ascending via shfl prefix over !mask
  int cnt = 0;
  #pragma unroll
  for (int j = 0; j < 4; ++j) cnt += (maskv[t * 4 + j] == 0);
  int inc = cnt;
  #pragma unroll
  for (int dd = 1; dd < 64; dd <<= 1) {
    const int o = __shfl_up(inc, dd);
    if (lane >= dd) inc += o;
  }
  if (lane == 63) wsumS[wv] = inc;
  __syncthreads();
  int basep = 0;
  for (int i = 0; i < 4; ++i) if (i < wv) basep += wsumS[i];
  int pos = basep + inc - cnt;               // exclusive prefix
  #pragma unroll
  for (int j = 0; j < 4; ++j) {
    const int i = t * 4 + j;
    if (!maskv[i]) unsel[pos++] = i;
  }
  __syncthreads();

  // random remaining via fixed permutation
  if (t < NREM) {
    const int u = unsel[perm.p[t]];
    int xx = u & 31, yy = u >> 5;
    if (xx < 1) xx = 1;
    if (yy < 1) yy = 1;
    out[r * PSEL + KSEL + t]               = xx;
    out[NROW * PSEL + r * PSEL + KSEL + t] = yy;
  }
}

// ---------------- host: JAX threefry2x32 (partitionable) ----------------
static inline uint32_t rotl32(uint32_t v, uint32_t n) { return (v << n) | (v >> (32 - n)); }

static void tf2x32(uint32_t k0, uint32_t k1, uint32_t x0, uint32_t x1,
                   uint32_t* o0, uint32_t* o1)
{
  const uint32_t ks[3] = { k0, k1, k0 ^ k1 ^ 0x1BD11BDAu };
  static const uint32_t rot[2][4] = { {13, 15, 26, 6}, {17, 29, 16, 24} };
  x0 += ks[0]; x1 += ks[1];
  for (int i = 0; i < 5; ++i) {
    const uint32_t* rr = rot[i & 1];
    for (int j = 0; j < 4; ++j) { x0 += x1; x1 = rotl32(x1, rr[j]); x1 ^= x0; }
    x0 += ks[(i + 1) % 3];
    x1 += ks[(i + 2) % 3] + (uint32_t)(i + 1);
  }
  *o0 = x0; *o1 = x1;
}

// perm = jax.random.permutation(jax.random.key(42), 1004)[:76]  (threefry_partitionable)
static void compute_perm(int* perm_out)
{
  uint32_t bits[NUNSEL];
  uint32_t sk0, sk1;
  { uint32_t o0, o1; tf2x32(0u, 42u, 0u, 1u, &o0, &o1); sk0 = o0; sk1 = o1; }
  for (int i = 0; i < NUNSEL; ++i) {
    uint32_t o0, o1; tf2x32(sk0, sk1, 0u, (uint32_t)i, &o0, &o1);
    bits[i] = o0 ^ o1;
  }
  int idx[NUNSEL];
  for (int i = 0; i < NUNSEL; ++i) idx[i] = i;
  std::stable_sort(idx, idx + NUNSEL, [&](int a, int b) { return bits[a] < bits[b]; });
  for (int j = 0; j < NREM; ++j) perm_out[j] = idx[j];
}

extern "C" void kernel_launch(void* const* d_in, const int* in_sizes, int n_in,
                              void* d_out, int out_size, void* d_ws, size_t ws_size,
                              hipStream_t stream)
{
  (void)in_sizes; (void)n_in; (void)out_size; (void)ws_size;
  const float* feat = (const float*)d_in[0];
  const float* dw_w = (const float*)d_in[1];
  // d_in[2] = dw_b (zeros; constant shift, ordering-irrelevant)
  const float* pw_w = (const float*)d_in[3];
  // d_in[4] = pw_b (constant shift, ordering-irrelevant)
  int*   out     = (int*)d_out;
  float* partial = (float*)d_ws;                                // 16*48*4 KB = 3 MB, fully rewritten
  u64*   cand    = (u64*)((char*)d_ws + (size_t)NROW * SPLIT * HW * sizeof(float)); // 16*160 u64

  Perm76 perm;
  compute_perm(perm.p);                      // deterministic host compute, kernel-arg baked

  pv_conv<<<NROW * SPLIT, 256, 0, stream>>>(feat, dw_w, pw_w, partial);
  pv_reduceTopk<<<128, 256, 0, stream>>>(partial, cand);
  pv_selectB2<<<NROW, 256, 0, stream>>>(cand, out, perm);
}